// Round 19
// baseline (1942.976 us; speedup 1.0000x reference)
//
#include <hip/hip_runtime.h>
#include <math.h>

#define NINP 64
#define NH 512
#define G4 2048   // 4*NH
#define T 64
#define BATCH 2048
#define LDIN 4097 // T*NINP+1
#define XCOLS 4096

typedef _Float16 half8 __attribute__((ext_vector_type(8)));
typedef float f32x4 __attribute__((ext_vector_type(4)));
typedef unsigned short ushort8 __attribute__((ext_vector_type(8)));

// fast transcendentals: v_exp_f32 + v_rcp_f32 (sat-safe at +-inf)
__device__ __forceinline__ float sigmf(float x) {
    return __builtin_amdgcn_rcpf(1.0f + __expf(-x));
}
__device__ __forceinline__ float tanhf_fast(float x) {
    return fmaf(-2.0f, __builtin_amdgcn_rcpf(1.0f + __expf(2.0f * x)), 1.0f);
}

__device__ __forceinline__ unsigned short f2h_bits(float f) {
    _Float16 h = (_Float16)f;
    return __builtin_bit_cast(unsigned short, h);
}
__device__ __forceinline__ float h_to_f(unsigned short b) {
    return (float)__builtin_bit_cast(_Float16, b);
}

// global -> LDS DMA, 16B per lane. LDS dest = wave-uniform base + lane*16.
__device__ __forceinline__ void gll16(const void* g, void* l) {
    __builtin_amdgcn_global_load_lds(
        (const __attribute__((address_space(1))) unsigned int*)g,
        (__attribute__((address_space(3))) unsigned int*)l, 16, 0, 0);
}

// ---------------------------------------------------------------------------
// R18 diagnosis: ~80% LDS-port-bound; reads/tile minimized by SQUARE wave
// tile. NEW geometry: 256 thr / 4 waves (2m x 2n), wave tile 64x64,
// acc[4][4]: 32 ds_read_b128 per 128x128x32 block-tile (-33% vs R18's 48).
// Single-fp16 A and W (R18 numerics, verified absmax 4.88e-4 of 2.675e-3).
// C = A*W, one MFMA pass. LDS: 2 x 16KB stage bufs (A 8KB + W 8KB) aliased
// under Gs[64][132] (33792 B) -> 3 blocks/CU co-resident.
// One dispatch per superstep [L2(s-3) | L1(s-2) | P1(s)].
// XOR swizzle baked into global layout (conflicts==0). vmcnt(4) pipeline.
// Gate columns PERMUTED: n' = j*4+g. 2D XCD partition. t=0: K1=0 + zc.
// HW transcendentals in epilogue.
// ---------------------------------------------------------------------------
#define OFF_W   4096   // ushorts
#define BUFSZ   8192   // ushorts per buffer (16384 B)

struct Job {
    const ushort *A0; int lda0;
    const ushort *W0; int K0;
    const ushort *A1; int lda1;
    const ushort *W1; int K1;
    const float *bias, *pv, *pc;
    float *c;
    ushort *hdst;
    const ushort *oph;
    float *piadst, *odst;
    int ostride, zc;
};

__global__ __launch_bounds__(256, 3) void lstm_fused3_k(
    Job j0, Job j1, Job j2, int nA, int nAB,
    const float* __restrict__ Wl, const float* __restrict__ blv,
    const float* __restrict__ input)
{
    __shared__ __align__(16) ushort smem[16896];   // 33792 B (2x16KB bufs; Gs [64][132])
    float* Gs = (float*)smem;

    const int tid = threadIdx.x;
    const int lane = tid & 63;
    const int wid = tid >> 6;        // 0..3

    Job j; int bid;
    if ((int)blockIdx.x < nA)       { j = j0; bid = blockIdx.x; }
    else if ((int)blockIdx.x < nAB) { j = j1; bid = blockIdx.x - nA; }
    else                            { j = j2; bid = blockIdx.x - nAB; }

    // 2D XCD-pinned tile mapping: xcd>>2 = m-half, xcd&3 = n-quarter
    const int xcd = bid & 7;
    const int loc = bid >> 3;                         // 0..31
    const int mblk = ((xcd >> 2) << 3) | (loc & 7);   // 0..15
    const int nblk = ((xcd & 3) << 2) | (loc >> 3);   // 0..15
    const int m0 = mblk * 128;
    const int n0 = nblk * 128;

    // ---- prologue: out-projection of previous h (2 rows per wave) ----
    if (j.oph != nullptr) {
        const float4* wv = (const float4*)(Wl + lane * 8);
        float4 w0 = wv[0], w1 = wv[1];
        float wreg[8] = {w0.x, w0.y, w0.z, w0.w, w1.x, w1.y, w1.z, w1.w};
        #pragma unroll
        for (int r2 = 0; r2 < 2; ++r2) {
            int row = bid * 8 + wid * 2 + r2;
            int xr = (row >> 1) & 3;
            int colp = ((lane >> 2) * 32) + (((lane & 3) ^ xr) << 3);
            ushort8 hh8 = *(const ushort8*)&j.oph[(size_t)row * NH + colp];
            float s = 0.f;
            #pragma unroll
            for (int e = 0; e < 8; ++e) s = fmaf(h_to_f(hh8[e]), wreg[e], s);
            #pragma unroll
            for (int off = 32; off > 0; off >>= 1) s += __shfl_down(s, off);
            if (lane == 0) {
                float proj = s + blv[0];
                if (j.odst) j.odst[(size_t)row * j.ostride] = proj;
                if (j.piadst) j.piadst[row] = fabsf(proj) * input[(size_t)row * LDIN + (LDIN - 1)];
            }
        }
    }

    // wave geometry: 2m x 2n, wave tile 64x64
    const int wm = wid >> 1;        // 0..1
    const int wn = wid & 1;         // 0..1
    const int fr = lane & 15;
    const int fg = lane >> 4;
    const int rdsw = (fr >> 1) & 3; // read swizzle (row bases multiple of 16)

    // staging geometry: 256 threads, 2 row-passes of 64 rows, planes A and W
    const int srow = tid >> 2;      // 0..63
    const int aslot = tid & 3;

    const int nt0 = j.K0 >> 5;
    const int nt1 = j.K1 >> 5;
    const int NT = nt0 + nt1;

    auto stage = [&](int t, int buf) {
        const ushort *Ap, *Wp;
        int lda_, K_, kt;
        if (t < nt0) { Ap = j.A0; lda_ = j.lda0; K_ = j.K0; kt = t * 32; Wp = j.W0; }
        else         { Ap = j.A1; lda_ = j.lda1; K_ = j.K1; kt = (t - nt0) * 32; Wp = j.W1; }
        char* base = (char*)smem + buf * 16384;
        const size_t acol = (size_t)kt + aslot * 8;
        #pragma unroll
        for (int cc = 0; cc < 2; ++cc) {
            int grow = cc * 64 + srow;
            char* wb = base + cc * 4096 + wid * 1024;
            gll16(&Ap[(size_t)(m0 + grow) * lda_ + acol], wb);
            gll16(&Wp[(size_t)(n0 + grow) * K_ + acol],   wb + 8192);
        }
    };

    f32x4 acc[4][4] = {};
    int cur = 0;

    stage(0, 0);
    if (NT > 1) stage(1, 1);

    for (int t = 0; t < NT; ++t) {
        // counted wait: all but the newest 4 loads (stage t+1)
        if (t + 1 < NT) { asm volatile("s_waitcnt vmcnt(4)" ::: "memory"); }
        else            { asm volatile("s_waitcnt vmcnt(0)" ::: "memory"); }
        __builtin_amdgcn_s_barrier();

        const ushort* bp = smem + cur * BUFSZ;
        half8 ah[4], wv[4];
        #pragma unroll
        for (int im = 0; im < 4; ++im) {
            int off = (wm * 64 + im * 16 + fr) * 32 + ((fg ^ rdsw) << 3);
            ah[im] = *(const half8*)&bp[off];
        }
        #pragma unroll
        for (int in = 0; in < 4; ++in) {
            int off = (wn * 64 + in * 16 + fr) * 32 + ((fg ^ rdsw) << 3);
            wv[in] = *(const half8*)&bp[OFF_W + off];
        }
        #pragma unroll
        for (int im = 0; im < 4; ++im)
            #pragma unroll
            for (int in = 0; in < 4; ++in)
                acc[im][in] = __builtin_amdgcn_mfma_f32_16x16x32_f16(ah[im], wv[in], acc[im][in], 0, 0, 0);

        asm volatile("" ::: "memory");
        __builtin_amdgcn_s_barrier();       // all waves done reading buf[cur]
        asm volatile("" ::: "memory");
        if (t + 2 < NT) stage(t + 2, cur);  // refill the buffer just consumed
        cur ^= 1;
    }

    // ---- epilogue: 2 chunks over im-pairs, Gs = [64][132] f32 aliased ----
    #pragma unroll
    for (int ch = 0; ch < 2; ++ch) {
        __syncthreads();   // stage-buffer reads (or prev chunk) done
        // stage 1: bias + pia, fragments im = {2ch, 2ch+1} -> Gs
        {
            #pragma unroll
            for (int q = 0; q < 2; ++q) {
                int im = ch * 2 + q;
                int g64 = wm * 32 + q * 16 + fg * 4;      // Gs row base
                int rowl = wm * 64 + im * 16 + fg * 4;    // global row base
                #pragma unroll
                for (int in = 0; in < 4; ++in) {
                    int npl = wn * 64 + in * 16 + fr;
                    int np = n0 + npl;
                    float bias = j.bias[np];
                    float pcv = (j.pc != nullptr) ? j.pc[np] : 0.0f;
                    #pragma unroll
                    for (int r = 0; r < 4; ++r) {
                        float g = acc[im][in][r] + bias;
                        if (j.pv != nullptr) g += j.pv[m0 + rowl + r] * pcv;
                        Gs[(g64 + r) * 132 + npl] = g;
                    }
                }
            }
        }
        __syncthreads();
        // stage 2: per-cell update (8 cells/thread), coalesced I/O
        {
            int r64 = tid >> 2;                  // 0..63 (Gs row)
            int jq = (tid & 3) * 8;              // 8 j's within 32-j block
            int brow = (r64 >> 5) * 64 + ch * 32 + (r64 & 31);
            int jbase = (n0 >> 2) + jq;
            size_t rowb = (size_t)(m0 + brow) * NH;
            size_t idx = rowb + jbase;
            float co[8];
            if (j.zc) {
                #pragma unroll
                for (int e = 0; e < 8; ++e) co[e] = 0.0f;
            } else {
                float4 c0 = *(const float4*)&j.c[idx];
                float4 c1 = *(const float4*)&j.c[idx + 4];
                co[0] = c0.x; co[1] = c0.y; co[2] = c0.z; co[3] = c0.w;
                co[4] = c1.x; co[5] = c1.y; co[6] = c1.z; co[7] = c1.w;
            }
            float cn[8], hn[8];
            #pragma unroll
            for (int jj = 0; jj < 8; ++jj) {
                float4 gv = *(const float4*)&Gs[r64 * 132 + (jq + jj) * 4];
                float cnv = sigmf(gv.y) * co[jj] + sigmf(gv.x) * tanhf_fast(gv.z);
                cn[jj] = cnv;
                hn[jj] = sigmf(gv.w) * tanhf_fast(cnv);
            }
            float4 cs0 = {cn[0], cn[1], cn[2], cn[3]};
            float4 cs1 = {cn[4], cn[5], cn[6], cn[7]};
            *(float4*)&j.c[idx] = cs0;
            *(float4*)&j.c[idx + 4] = cs1;
            ushort8 hh;
            #pragma unroll
            for (int e = 0; e < 8; ++e) hh[e] = f2h_bits(hn[e]);
            int xb = (brow >> 1) & 3;
            int colp = (jbase & ~31) | ((((jbase >> 3) & 3) ^ xb) << 3);
            *(ushort8*)&j.hdst[rowb + colp] = hh;
        }
    }
}

// Standalone out-projection from XOR-permuted fp16 h, optional pia.
__global__ __launch_bounds__(256) void out_proj_hl(const ushort* __restrict__ hsrc,
                                                   const float* __restrict__ Wl,
                                                   const float* __restrict__ blv,
                                                   const float* __restrict__ scaleBase,
                                                   float* __restrict__ piadst,
                                                   float* __restrict__ odst, int ostride)
{
    int wave = threadIdx.x >> 6;
    int lane = threadIdx.x & 63;
    int row = blockIdx.x * 4 + wave;
    int xr = (row >> 1) & 3;
    int colp = ((lane >> 2) * 32) + (((lane & 3) ^ xr) << 3);
    ushort8 hh8 = *(const ushort8*)&hsrc[(size_t)row * NH + colp];
    const float4* wv = (const float4*)(Wl + lane * 8);
    float4 w0 = wv[0], w1 = wv[1];
    float wreg[8] = {w0.x, w0.y, w0.z, w0.w, w1.x, w1.y, w1.z, w1.w};
    float s = 0.f;
    #pragma unroll
    for (int e = 0; e < 8; ++e) s = fmaf(h_to_f(hh8[e]), wreg[e], s);
    #pragma unroll
    for (int off = 32; off > 0; off >>= 1) s += __shfl_down(s, off);
    if (lane == 0) {
        float proj = s + blv[0];
        if (odst) odst[(size_t)row * ostride] = proj;
        if (piadst) piadst[row] = fabsf(proj) * scaleBase[(size_t)row * LDIN + (LDIN - 1)];
    }
}

// Split W[4NH][ldw] into permuted SINGLE fp16 plane, n' = j*4+g, with
// XOR-permuted 8-elem groups within each 32-col K-block.
__global__ __launch_bounds__(256) void split_perm_w_k(const float* __restrict__ W,
                                                      ushort* __restrict__ wout,
                                                      int ldw, int kshift)
{
    int idx = blockIdx.x * 256 + threadIdx.x;
    int K = 1 << kshift;
    int np = idx >> kshift;
    int k = idx & (K - 1);
    int ks = (k & ~31) | ((((k >> 3) & 3) ^ ((np >> 1) & 3)) << 3) | (k & 7);
    int orig = ((np & 3) << 9) | (np >> 2);
    wout[idx] = f2h_bits(W[(size_t)orig * ldw + ks]);
}

// Convert input x to fp16 [b][4096], XOR-permuted groups per 32-block.
__global__ __launch_bounds__(256) void split_x_k(const float* __restrict__ input,
                                                 ushort* __restrict__ xh)
{
    int idx = blockIdx.x * 256 + threadIdx.x;   // over BATCH*XCOLS
    int b = idx >> 12;
    int col = idx & (XCOLS - 1);
    int cs = (col & ~31) | ((((col >> 3) & 3) ^ ((b >> 1) & 3)) << 3) | (col & 7);
    xh[idx] = f2h_bits(input[(size_t)b * LDIN + cs]);
}

__global__ __launch_bounds__(256) void bias_prep_k(const float* __restrict__ bih,
                                                   const float* __restrict__ bhh,
                                                   float* __restrict__ bperm)
{
    int np = blockIdx.x * 256 + threadIdx.x;
    int orig = ((np & 3) << 9) | (np >> 2);
    bperm[np] = bih[orig] + bhh[orig];
}

__global__ __launch_bounds__(256) void pc_prep_k(const float* __restrict__ Wih1,
                                                 float* __restrict__ pc)
{
    int np = blockIdx.x * 256 + threadIdx.x;
    int orig = ((np & 3) << 9) | (np >> 2);
    pc[np] = Wih1[(size_t)orig * (NINP + 1) + NINP];
}

extern "C" void kernel_launch(void* const* d_in, const int* in_sizes, int n_in,
                              void* d_out, int out_size, void* d_ws, size_t ws_size,
                              hipStream_t stream)
{
    const float* input = (const float*)d_in[0];
    const float* Wih_p = (const float*)d_in[1];
    const float* Whh_p = (const float*)d_in[2];
    const float* bih_p = (const float*)d_in[3];
    const float* bhh_p = (const float*)d_in[4];
    const float* Wih1  = (const float*)d_in[5];
    const float* Whh1  = (const float*)d_in[6];
    const float* bih1  = (const float*)d_in[7];
    const float* bhh1  = (const float*)d_in[8];
    const float* Wih2  = (const float*)d_in[9];
    const float* Whh2  = (const float*)d_in[10];
    const float* bih2  = (const float*)d_in[11];
    const float* bhh2  = (const float*)d_in[12];
    const float* Wl    = (const float*)d_in[13];
    const float* bl    = (const float*)d_in[14];
    float* out = (float*)d_out;

    const size_t HC = (size_t)BATCH * NH;       // 1M elems
    char* p = (char*)d_ws;
    auto alloc = [&](size_t bytes) { char* r = p; p += (bytes + 255) & ~(size_t)255; return r; };

    float* c_p = (float*)alloc(HC * 4);
    float* c1  = (float*)alloc(HC * 4);
    float* c2  = (float*)alloc(HC * 4);
    ushort* hps[2]; ushort* h1s[2]; ushort* h2s[2];
    for (int i = 0; i < 2; ++i) hps[i] = (ushort*)alloc(HC * 2);
    for (int i = 0; i < 2; ++i) h1s[i] = (ushort*)alloc(HC * 2);
    for (int i = 0; i < 2; ++i) h2s[i] = (ushort*)alloc(HC * 2);
    float* pias   = (float*)alloc((size_t)T * BATCH * 4);
    ushort* WhhP_h = (ushort*)alloc((size_t)G4 * NH * 2);
    ushort* WihP_h = (ushort*)alloc((size_t)G4 * NINP * 2);
    ushort* Whh1_h = (ushort*)alloc((size_t)G4 * NH * 2);
    ushort* Wih1x_h = (ushort*)alloc((size_t)G4 * NINP * 2);
    ushort* Wih2_h = (ushort*)alloc((size_t)G4 * NH * 2);
    ushort* Whh2_h = (ushort*)alloc((size_t)G4 * NH * 2);
    ushort* xh = (ushort*)alloc((size_t)BATCH * XCOLS * 2);
    float* biasP = (float*)alloc(G4 * 4);
    float* bias1 = (float*)alloc(G4 * 4);
    float* bias2 = (float*)alloc(G4 * 4);
    float* pc1   = (float*)alloc(G4 * 4);

    // prep (no memset: t=0 jobs skip h-segments via K=0 and zero c via zc)
    split_perm_w_k<<<(G4 * NH) / 256, 256, 0, stream>>>(Whh_p, WhhP_h, NH, 9);
    split_perm_w_k<<<(G4 * NINP) / 256, 256, 0, stream>>>(Wih_p, WihP_h, NINP, 6);
    split_perm_w_k<<<(G4 * NH) / 256, 256, 0, stream>>>(Whh1, Whh1_h, NH, 9);
    split_perm_w_k<<<(G4 * NINP) / 256, 256, 0, stream>>>(Wih1, Wih1x_h, NINP + 1, 6);
    split_perm_w_k<<<(G4 * NH) / 256, 256, 0, stream>>>(Wih2, Wih2_h, NH, 9);
    split_perm_w_k<<<(G4 * NH) / 256, 256, 0, stream>>>(Whh2, Whh2_h, NH, 9);
    split_x_k<<<(BATCH * XCOLS) / 256, 256, 0, stream>>>(input, xh);
    bias_prep_k<<<G4 / 256, 256, 0, stream>>>(bih_p, bhh_p, biasP);
    bias_prep_k<<<G4 / 256, 256, 0, stream>>>(bih1, bhh1, bias1);
    bias_prep_k<<<G4 / 256, 256, 0, stream>>>(bih2, bhh2, bias2);
    pc_prep_k<<<G4 / 256, 256, 0, stream>>>(Wih1, pc1);

    auto jobP1 = [&](int s) {
        Job jo = {};
        jo.A0 = xh + (size_t)s * NINP; jo.lda0 = XCOLS;
        jo.W0 = WihP_h; jo.K0 = NINP;
        jo.A1 = hps[s & 1]; jo.lda1 = NH;
        jo.W1 = WhhP_h; jo.K1 = (s == 0) ? 0 : NH;
        jo.bias = biasP; jo.pv = nullptr; jo.pc = nullptr;
        jo.c = c_p; jo.hdst = hps[(s + 1) & 1];
        jo.oph = (s > 0) ? hps[s & 1] : nullptr;
        jo.piadst = (s > 0) ? (pias + (size_t)(s - 1) * BATCH) : nullptr;
        jo.odst = nullptr; jo.ostride = 0; jo.zc = (s == 0);
        return jo;
    };
    auto jobL1 = [&](int t) {
        Job jo = {};
        jo.A0 = xh + (size_t)t * NINP; jo.lda0 = XCOLS;
        jo.W0 = Wih1x_h; jo.K0 = NINP;
        jo.A1 = h1s[t & 1]; jo.lda1 = NH;
        jo.W1 = Whh1_h; jo.K1 = (t == 0) ? 0 : NH;
        jo.bias = bias1; jo.pv = pias + (size_t)t * BATCH; jo.pc = pc1;
        jo.c = c1; jo.hdst = h1s[(t + 1) & 1];
        jo.oph = nullptr;
        jo.piadst = nullptr; jo.odst = nullptr; jo.ostride = 0;
        jo.zc = (t == 0);
        return jo;
    };
    auto jobL2 = [&](int t) {
        Job jo = {};
        jo.A0 = h1s[(t + 1) & 1]; jo.lda0 = NH;
        jo.W0 = Wih2_h; jo.K0 = NH;
        jo.A1 = h2s[t & 1]; jo.lda1 = NH;
        jo.W1 = Whh2_h; jo.K1 = (t == 0) ? 0 : NH;
        jo.bias = bias2; jo.pv = nullptr; jo.pc = nullptr;
        jo.c = c2; jo.hdst = h2s[(t + 1) & 1];
        jo.oph = (t > 0) ? h2s[t & 1] : nullptr;
        jo.piadst = nullptr;
        jo.odst = (t > 0) ? (out + (t - 1)) : nullptr; jo.ostride = T + 1;
        jo.zc = (t == 0);
        return jo;
    };

    // One dispatch per superstep s: [L2(s-3) | L1(s-2) | P1(s)], 3 blocks/CU.
    for (int s = 0; s <= 66; ++s) {
        int nL2 = (s >= 3) ? 256 : 0;
        int nL1 = (s >= 2 && s <= 65) ? 256 : 0;
        int nP1 = (s <= 63) ? 256 : 0;
        Job j0 = {}, j1 = {}, j2 = {};
        if (nL2) j0 = jobL2(s - 3);
        if (nL1) j1 = jobL1(s - 2);
        if (nP1) j2 = jobP1(s);
        int nA = nL2, nAB = nL2 + nL1, total = nL2 + nL1 + nP1;
        lstm_fused3_k<<<total, 256, 0, stream>>>(j0, j1, j2, nA, nAB, Wl, bl, input);
        if (s == 63) {
            // T1: h_p(64) ready -> pias[63] (used by L1(63) at s=65) and raw
            // last_pia column out[:,T].
            out_proj_hl<<<BATCH / 4, 256, 0, stream>>>(hps[0], Wl, bl, input,
                                                       pias + (size_t)63 * BATCH,
                                                       out + T, T + 1);
        }
    }
    // T4: proj h2(64) -> out[:,63].
    out_proj_hl<<<BATCH / 4, 256, 0, stream>>>(h2s[0], Wl, bl, input,
                                               nullptr, out + 63, T + 1);
}

// Round 20
// 1893.899 us; speedup vs baseline: 1.0259x; 1.0259x over previous
//
#include <hip/hip_runtime.h>
#include <math.h>

#define NINP 64
#define NH 512
#define G4 2048   // 4*NH
#define T 64
#define BATCH 2048
#define LDIN 4097 // T*NINP+1
#define XCOLS 4096

typedef _Float16 half8 __attribute__((ext_vector_type(8)));
typedef float f32x4 __attribute__((ext_vector_type(4)));
typedef unsigned short ushort8 __attribute__((ext_vector_type(8)));
typedef unsigned short ushort4v __attribute__((ext_vector_type(4)));

// fast transcendentals: v_exp_f32 + v_rcp_f32 (sat-safe at +-inf)
__device__ __forceinline__ float sigmf(float x) {
    return __builtin_amdgcn_rcpf(1.0f + __expf(-x));
}
__device__ __forceinline__ float tanhf_fast(float x) {
    return fmaf(-2.0f, __builtin_amdgcn_rcpf(1.0f + __expf(2.0f * x)), 1.0f);
}

__device__ __forceinline__ unsigned short f2h_bits(float f) {
    _Float16 h = (_Float16)f;
    return __builtin_bit_cast(unsigned short, h);
}
__device__ __forceinline__ float h_to_f(unsigned short b) {
    return (float)__builtin_bit_cast(_Float16, b);
}

// global -> LDS DMA, 16B per lane. LDS dest = wave-uniform base + lane*16.
__device__ __forceinline__ void gll16(const void* g, void* l) {
    __builtin_amdgcn_global_load_lds(
        (const __attribute__((address_space(1))) unsigned int*)g,
        (__attribute__((address_space(3))) unsigned int*)l, 16, 0, 0);
}

// ---------------------------------------------------------------------------
// BEST CONFIG (R18, 1.89 ms): single-fp16 A and W, C = A*W (one MFMA pass).
// Geometry: 512 thr / 8 waves (4m x 2n), block tile 128x128, wave 32x64,
// acc[2][4], BK=32. LDS: 2 x 16KB stage bufs aliased under Gs[64][132]
// (33792 B total) -> 3 blocks/CU co-resident.
// One dispatch per superstep [L2(s-3) | L1(s-2) | P1(s)], all co-resident.
// XOR swizzle baked into global layout (conflicts==0). vmcnt(2) pipeline.
// Gate columns PERMUTED: n' = j*4+g. 2D XCD partition. t=0: K1=0 + zc.
// HW transcendentals in epilogue. (R19's 64x64/4-wave variant regressed:
// read-count win < TLP loss at ~80% LDS-port utilization.)
// ---------------------------------------------------------------------------
#define OFF_W   4096   // ushorts
#define BUFSZ   8192   // ushorts per buffer (16384 B)

struct Job {
    const ushort *A0; int lda0;
    const ushort *W0; int K0;
    const ushort *A1; int lda1;
    const ushort *W1; int K1;
    const float *bias, *pv, *pc;
    float *c;
    ushort *hdst;
    const ushort *oph;
    float *piadst, *odst;
    int ostride, zc;
};

__global__ __launch_bounds__(512, 6) void lstm_fused3_k(
    Job j0, Job j1, Job j2, int nA, int nAB,
    const float* __restrict__ Wl, const float* __restrict__ blv,
    const float* __restrict__ input)
{
    __shared__ __align__(16) ushort smem[16896];   // 33792 B (2x16KB bufs; Gs [64][132])
    float* Gs = (float*)smem;

    const int tid = threadIdx.x;
    const int lane = tid & 63;
    const int wid = tid >> 6;        // 0..7

    Job j; int bid;
    if ((int)blockIdx.x < nA)       { j = j0; bid = blockIdx.x; }
    else if ((int)blockIdx.x < nAB) { j = j1; bid = blockIdx.x - nA; }
    else                            { j = j2; bid = blockIdx.x - nAB; }

    // 2D XCD-pinned tile mapping: xcd>>2 = m-half, xcd&3 = n-quarter
    const int xcd = bid & 7;
    const int loc = bid >> 3;                         // 0..31
    const int mblk = ((xcd >> 2) << 3) | (loc & 7);   // 0..15
    const int nblk = ((xcd & 3) << 2) | (loc >> 3);   // 0..15
    const int m0 = mblk * 128;
    const int n0 = nblk * 128;

    // ---- prologue: out-projection of previous h (1 row per wave) ----
    if (j.oph != nullptr) {
        int row = bid * 8 + wid;
        int xr = (row >> 1) & 3;
        int colp = ((lane >> 2) * 32) + (((lane & 3) ^ xr) << 3);
        ushort8 hh8 = *(const ushort8*)&j.oph[(size_t)row * NH + colp];
        const float4* wv = (const float4*)(Wl + lane * 8);
        float4 w0 = wv[0], w1 = wv[1];
        float wreg[8] = {w0.x, w0.y, w0.z, w0.w, w1.x, w1.y, w1.z, w1.w};
        float s = 0.f;
        #pragma unroll
        for (int e = 0; e < 8; ++e) s = fmaf(h_to_f(hh8[e]), wreg[e], s);
        #pragma unroll
        for (int off = 32; off > 0; off >>= 1) s += __shfl_down(s, off);
        if (lane == 0) {
            float proj = s + blv[0];
            if (j.odst) j.odst[(size_t)row * j.ostride] = proj;
            if (j.piadst) j.piadst[row] = fabsf(proj) * input[(size_t)row * LDIN + (LDIN - 1)];
        }
    }

    // wave geometry: 4m x 2n, wave tile 32x64
    const int wm = wid >> 1;        // 0..3
    const int wn = wid & 1;         // 0..1
    const int fr = lane & 15;
    const int fg = lane >> 4;
    const int rdsw = (fr >> 1) & 3; // read swizzle (row bases multiple of 16)

    // staging geometry: 512 threads, 1 gll16 per plane (A, W)
    const int srow = tid >> 2;      // 0..127
    const int aslot = tid & 3;

    const int nt0 = j.K0 >> 5;
    const int nt1 = j.K1 >> 5;
    const int NT = nt0 + nt1;

    auto stage = [&](int t, int buf) {
        const ushort *Ap, *Wp;
        int lda_, K_, kt;
        if (t < nt0) { Ap = j.A0; lda_ = j.lda0; K_ = j.K0; kt = t * 32; Wp = j.W0; }
        else         { Ap = j.A1; lda_ = j.lda1; K_ = j.K1; kt = (t - nt0) * 32; Wp = j.W1; }
        char* wb = (char*)smem + buf * 16384 + wid * 1024;
        const size_t acol = (size_t)kt + aslot * 8;
        gll16(&Ap[(size_t)(m0 + srow) * lda_ + acol], wb);
        gll16(&Wp[(size_t)(n0 + srow) * K_ + acol],   wb + 8192);
    };

    f32x4 acc[2][4] = {};
    int cur = 0;

    stage(0, 0);
    if (NT > 1) stage(1, 1);

    for (int t = 0; t < NT; ++t) {
        // counted wait: all but the newest 2 loads (stage t+1)
        if (t + 1 < NT) { asm volatile("s_waitcnt vmcnt(2)" ::: "memory"); }
        else            { asm volatile("s_waitcnt vmcnt(0)" ::: "memory"); }
        __builtin_amdgcn_s_barrier();

        const ushort* bp = smem + cur * BUFSZ;
        half8 ah[2], wv[4];
        #pragma unroll
        for (int im = 0; im < 2; ++im) {
            int off = (wm * 32 + im * 16 + fr) * 32 + ((fg ^ rdsw) << 3);
            ah[im] = *(const half8*)&bp[off];
        }
        #pragma unroll
        for (int in = 0; in < 4; ++in) {
            int off = (wn * 64 + in * 16 + fr) * 32 + ((fg ^ rdsw) << 3);
            wv[in] = *(const half8*)&bp[OFF_W + off];
        }
        #pragma unroll
        for (int im = 0; im < 2; ++im)
            #pragma unroll
            for (int in = 0; in < 4; ++in)
                acc[im][in] = __builtin_amdgcn_mfma_f32_16x16x32_f16(ah[im], wv[in], acc[im][in], 0, 0, 0);

        asm volatile("" ::: "memory");
        __builtin_amdgcn_s_barrier();       // all waves done reading buf[cur]
        asm volatile("" ::: "memory");
        if (t + 2 < NT) stage(t + 2, cur);  // refill the buffer just consumed
        cur ^= 1;
    }

    // ---- epilogue: 2 chunks (im = 0,1), Gs = [64][132] f32 aliased ----
    #pragma unroll
    for (int ch = 0; ch < 2; ++ch) {
        __syncthreads();   // stage-buffer reads (or prev chunk) done
        // stage 1: bias + pia, fragments of chunk ch -> Gs
        {
            int g64 = wm * 16 + fg * 4;               // Gs row base
            int rowl = wm * 32 + ch * 16 + fg * 4;    // global row base
            #pragma unroll
            for (int in = 0; in < 4; ++in) {
                int npl = wn * 64 + in * 16 + fr;
                int np = n0 + npl;
                float bias = j.bias[np];
                float pcv = (j.pc != nullptr) ? j.pc[np] : 0.0f;
                #pragma unroll
                for (int r = 0; r < 4; ++r) {
                    float g = acc[ch][in][r] + bias;
                    if (j.pv != nullptr) g += j.pv[m0 + rowl + r] * pcv;
                    Gs[(g64 + r) * 132 + npl] = g;
                }
            }
        }
        __syncthreads();
        // stage 2: per-cell update (4 cells/thread), coalesced I/O
        {
            int r64 = tid >> 3;                  // 0..63 (Gs row)
            int jq = (tid & 7) * 4;              // j-quad within 32-j block
            int brow = (r64 >> 4) * 32 + ch * 16 + (r64 & 15);
            int jbase = (n0 >> 2) + jq;
            size_t rowb = (size_t)(m0 + brow) * NH;
            size_t idx = rowb + jbase;
            float co[4];
            if (j.zc) {
                co[0] = co[1] = co[2] = co[3] = 0.0f;
            } else {
                float4 c0 = *(const float4*)&j.c[idx];
                co[0] = c0.x; co[1] = c0.y; co[2] = c0.z; co[3] = c0.w;
            }
            float cn[4], hn[4];
            #pragma unroll
            for (int jj = 0; jj < 4; ++jj) {
                float4 gv = *(const float4*)&Gs[r64 * 132 + (jq + jj) * 4];
                float cnv = sigmf(gv.y) * co[jj] + sigmf(gv.x) * tanhf_fast(gv.z);
                cn[jj] = cnv;
                hn[jj] = sigmf(gv.w) * tanhf_fast(cnv);
            }
            float4 cs = {cn[0], cn[1], cn[2], cn[3]};
            *(float4*)&j.c[idx] = cs;
            ushort4v hh;
            #pragma unroll
            for (int e = 0; e < 4; ++e) hh[e] = f2h_bits(hn[e]);
            int xb = (brow >> 1) & 3;
            int colp = (jbase & ~31) | ((((jbase >> 3) & 3) ^ xb) << 3) | (jbase & 7);
            *(ushort4v*)&j.hdst[rowb + colp] = hh;
        }
    }
}

// Standalone out-projection from XOR-permuted fp16 h, optional pia.
__global__ __launch_bounds__(256) void out_proj_hl(const ushort* __restrict__ hsrc,
                                                   const float* __restrict__ Wl,
                                                   const float* __restrict__ blv,
                                                   const float* __restrict__ scaleBase,
                                                   float* __restrict__ piadst,
                                                   float* __restrict__ odst, int ostride)
{
    int wave = threadIdx.x >> 6;
    int lane = threadIdx.x & 63;
    int row = blockIdx.x * 4 + wave;
    int xr = (row >> 1) & 3;
    int colp = ((lane >> 2) * 32) + (((lane & 3) ^ xr) << 3);
    ushort8 hh8 = *(const ushort8*)&hsrc[(size_t)row * NH + colp];
    const float4* wv = (const float4*)(Wl + lane * 8);
    float4 w0 = wv[0], w1 = wv[1];
    float wreg[8] = {w0.x, w0.y, w0.z, w0.w, w1.x, w1.y, w1.z, w1.w};
    float s = 0.f;
    #pragma unroll
    for (int e = 0; e < 8; ++e) s = fmaf(h_to_f(hh8[e]), wreg[e], s);
    #pragma unroll
    for (int off = 32; off > 0; off >>= 1) s += __shfl_down(s, off);
    if (lane == 0) {
        float proj = s + blv[0];
        if (odst) odst[(size_t)row * ostride] = proj;
        if (piadst) piadst[row] = fabsf(proj) * scaleBase[(size_t)row * LDIN + (LDIN - 1)];
    }
}

// Split W[4NH][ldw] into permuted SINGLE fp16 plane, n' = j*4+g, with
// XOR-permuted 8-elem groups within each 32-col K-block.
__global__ __launch_bounds__(256) void split_perm_w_k(const float* __restrict__ W,
                                                      ushort* __restrict__ wout,
                                                      int ldw, int kshift)
{
    int idx = blockIdx.x * 256 + threadIdx.x;
    int K = 1 << kshift;
    int np = idx >> kshift;
    int k = idx & (K - 1);
    int ks = (k & ~31) | ((((k >> 3) & 3) ^ ((np >> 1) & 3)) << 3) | (k & 7);
    int orig = ((np & 3) << 9) | (np >> 2);
    wout[idx] = f2h_bits(W[(size_t)orig * ldw + ks]);
}

// Convert input x to fp16 [b][4096], XOR-permuted groups per 32-block.
__global__ __launch_bounds__(256) void split_x_k(const float* __restrict__ input,
                                                 ushort* __restrict__ xh)
{
    int idx = blockIdx.x * 256 + threadIdx.x;   // over BATCH*XCOLS
    int b = idx >> 12;
    int col = idx & (XCOLS - 1);
    int cs = (col & ~31) | ((((col >> 3) & 3) ^ ((b >> 1) & 3)) << 3) | (col & 7);
    xh[idx] = f2h_bits(input[(size_t)b * LDIN + cs]);
}

__global__ __launch_bounds__(256) void bias_prep_k(const float* __restrict__ bih,
                                                   const float* __restrict__ bhh,
                                                   float* __restrict__ bperm)
{
    int np = blockIdx.x * 256 + threadIdx.x;
    int orig = ((np & 3) << 9) | (np >> 2);
    bperm[np] = bih[orig] + bhh[orig];
}

__global__ __launch_bounds__(256) void pc_prep_k(const float* __restrict__ Wih1,
                                                 float* __restrict__ pc)
{
    int np = blockIdx.x * 256 + threadIdx.x;
    int orig = ((np & 3) << 9) | (np >> 2);
    pc[np] = Wih1[(size_t)orig * (NINP + 1) + NINP];
}

extern "C" void kernel_launch(void* const* d_in, const int* in_sizes, int n_in,
                              void* d_out, int out_size, void* d_ws, size_t ws_size,
                              hipStream_t stream)
{
    const float* input = (const float*)d_in[0];
    const float* Wih_p = (const float*)d_in[1];
    const float* Whh_p = (const float*)d_in[2];
    const float* bih_p = (const float*)d_in[3];
    const float* bhh_p = (const float*)d_in[4];
    const float* Wih1  = (const float*)d_in[5];
    const float* Whh1  = (const float*)d_in[6];
    const float* bih1  = (const float*)d_in[7];
    const float* bhh1  = (const float*)d_in[8];
    const float* Wih2  = (const float*)d_in[9];
    const float* Whh2  = (const float*)d_in[10];
    const float* bih2  = (const float*)d_in[11];
    const float* bhh2  = (const float*)d_in[12];
    const float* Wl    = (const float*)d_in[13];
    const float* bl    = (const float*)d_in[14];
    float* out = (float*)d_out;

    const size_t HC = (size_t)BATCH * NH;       // 1M elems
    char* p = (char*)d_ws;
    auto alloc = [&](size_t bytes) { char* r = p; p += (bytes + 255) & ~(size_t)255; return r; };

    float* c_p = (float*)alloc(HC * 4);
    float* c1  = (float*)alloc(HC * 4);
    float* c2  = (float*)alloc(HC * 4);
    ushort* hps[2]; ushort* h1s[2]; ushort* h2s[2];
    for (int i = 0; i < 2; ++i) hps[i] = (ushort*)alloc(HC * 2);
    for (int i = 0; i < 2; ++i) h1s[i] = (ushort*)alloc(HC * 2);
    for (int i = 0; i < 2; ++i) h2s[i] = (ushort*)alloc(HC * 2);
    float* pias   = (float*)alloc((size_t)T * BATCH * 4);
    ushort* WhhP_h = (ushort*)alloc((size_t)G4 * NH * 2);
    ushort* WihP_h = (ushort*)alloc((size_t)G4 * NINP * 2);
    ushort* Whh1_h = (ushort*)alloc((size_t)G4 * NH * 2);
    ushort* Wih1x_h = (ushort*)alloc((size_t)G4 * NINP * 2);
    ushort* Wih2_h = (ushort*)alloc((size_t)G4 * NH * 2);
    ushort* Whh2_h = (ushort*)alloc((size_t)G4 * NH * 2);
    ushort* xh = (ushort*)alloc((size_t)BATCH * XCOLS * 2);
    float* biasP = (float*)alloc(G4 * 4);
    float* bias1 = (float*)alloc(G4 * 4);
    float* bias2 = (float*)alloc(G4 * 4);
    float* pc1   = (float*)alloc(G4 * 4);

    // prep (no memset: t=0 jobs skip h-segments via K=0 and zero c via zc)
    split_perm_w_k<<<(G4 * NH) / 256, 256, 0, stream>>>(Whh_p, WhhP_h, NH, 9);
    split_perm_w_k<<<(G4 * NINP) / 256, 256, 0, stream>>>(Wih_p, WihP_h, NINP, 6);
    split_perm_w_k<<<(G4 * NH) / 256, 256, 0, stream>>>(Whh1, Whh1_h, NH, 9);
    split_perm_w_k<<<(G4 * NINP) / 256, 256, 0, stream>>>(Wih1, Wih1x_h, NINP + 1, 6);
    split_perm_w_k<<<(G4 * NH) / 256, 256, 0, stream>>>(Wih2, Wih2_h, NH, 9);
    split_perm_w_k<<<(G4 * NH) / 256, 256, 0, stream>>>(Whh2, Whh2_h, NH, 9);
    split_x_k<<<(BATCH * XCOLS) / 256, 256, 0, stream>>>(input, xh);
    bias_prep_k<<<G4 / 256, 256, 0, stream>>>(bih_p, bhh_p, biasP);
    bias_prep_k<<<G4 / 256, 256, 0, stream>>>(bih1, bhh1, bias1);
    bias_prep_k<<<G4 / 256, 256, 0, stream>>>(bih2, bhh2, bias2);
    pc_prep_k<<<G4 / 256, 256, 0, stream>>>(Wih1, pc1);

    auto jobP1 = [&](int s) {
        Job jo = {};
        jo.A0 = xh + (size_t)s * NINP; jo.lda0 = XCOLS;
        jo.W0 = WihP_h; jo.K0 = NINP;
        jo.A1 = hps[s & 1]; jo.lda1 = NH;
        jo.W1 = WhhP_h; jo.K1 = (s == 0) ? 0 : NH;
        jo.bias = biasP; jo.pv = nullptr; jo.pc = nullptr;
        jo.c = c_p; jo.hdst = hps[(s + 1) & 1];
        jo.oph = (s > 0) ? hps[s & 1] : nullptr;
        jo.piadst = (s > 0) ? (pias + (size_t)(s - 1) * BATCH) : nullptr;
        jo.odst = nullptr; jo.ostride = 0; jo.zc = (s == 0);
        return jo;
    };
    auto jobL1 = [&](int t) {
        Job jo = {};
        jo.A0 = xh + (size_t)t * NINP; jo.lda0 = XCOLS;
        jo.W0 = Wih1x_h; jo.K0 = NINP;
        jo.A1 = h1s[t & 1]; jo.lda1 = NH;
        jo.W1 = Whh1_h; jo.K1 = (t == 0) ? 0 : NH;
        jo.bias = bias1; jo.pv = pias + (size_t)t * BATCH; jo.pc = pc1;
        jo.c = c1; jo.hdst = h1s[(t + 1) & 1];
        jo.oph = nullptr;
        jo.piadst = nullptr; jo.odst = nullptr; jo.ostride = 0;
        jo.zc = (t == 0);
        return jo;
    };
    auto jobL2 = [&](int t) {
        Job jo = {};
        jo.A0 = h1s[(t + 1) & 1]; jo.lda0 = NH;
        jo.W0 = Wih2_h; jo.K0 = NH;
        jo.A1 = h2s[t & 1]; jo.lda1 = NH;
        jo.W1 = Whh2_h; jo.K1 = (t == 0) ? 0 : NH;
        jo.bias = bias2; jo.pv = nullptr; jo.pc = nullptr;
        jo.c = c2; jo.hdst = h2s[(t + 1) & 1];
        jo.oph = (t > 0) ? h2s[t & 1] : nullptr;
        jo.piadst = nullptr;
        jo.odst = (t > 0) ? (out + (t - 1)) : nullptr; jo.ostride = T + 1;
        jo.zc = (t == 0);
        return jo;
    };

    // One dispatch per superstep s: [L2(s-3) | L1(s-2) | P1(s)], 3 blocks/CU.
    for (int s = 0; s <= 66; ++s) {
        int nL2 = (s >= 3) ? 256 : 0;
        int nL1 = (s >= 2 && s <= 65) ? 256 : 0;
        int nP1 = (s <= 63) ? 256 : 0;
        Job j0 = {}, j1 = {}, j2 = {};
        if (nL2) j0 = jobL2(s - 3);
        if (nL1) j1 = jobL1(s - 2);
        if (nP1) j2 = jobP1(s);
        int nA = nL2, nAB = nL2 + nL1, total = nL2 + nL1 + nP1;
        lstm_fused3_k<<<total, 512, 0, stream>>>(j0, j1, j2, nA, nAB, Wl, bl, input);
        if (s == 63) {
            // T1: h_p(64) ready -> pias[63] (used by L1(63) at s=65) and raw
            // last_pia column out[:,T].
            out_proj_hl<<<BATCH / 4, 256, 0, stream>>>(hps[0], Wl, bl, input,
                                                       pias + (size_t)63 * BATCH,
                                                       out + T, T + 1);
        }
    }
    // T4: proj h2(64) -> out[:,63].
    out_proj_hl<<<BATCH / 4, 256, 0, stream>>>(h2s[0], Wl, bl, input,
                                               nullptr, out + 63, T + 1);
}